// Round 7
// baseline (327.490 us; speedup 1.0000x reference)
//
#include <hip/hip_runtime.h>

#define B_ 2
#define S_ 2048
#define E_ 1024
#define H_ 16
#define DH 64
#define MM (B_*S_)   // 4096
#define BHN (B_*H_)  // 32

typedef unsigned short u16;
typedef unsigned int u32;
typedef __attribute__((ext_vector_type(8))) __bf16 bf16x8;
typedef __attribute__((ext_vector_type(4))) float f32x4;
typedef __attribute__((ext_vector_type(8))) u16 u16x8;
typedef __attribute__((ext_vector_type(4))) u16 u16x4;

static __device__ __forceinline__ u16 f2bf(float f) {
  u32 u = __builtin_bit_cast(u32, f);
  u += 0x7fffu + ((u >> 16) & 1u);
  return (u16)(u >> 16);
}
static __device__ __forceinline__ float bf2f(u16 h) {
  return __builtin_bit_cast(float, (u32)h << 16);
}
// XOR swizzle for 128B-stride row-major LDS tiles.
static __device__ __forceinline__ u32 sw(u32 byte) {
  return byte ^ (((byte >> 7) & 7u) << 4);
}
static __device__ __forceinline__ bf16x8 frag(const u16* lds, u32 byte) {
  return *(const bf16x8*)((const char*)lds + byte);
}
static __device__ __forceinline__ f32x4 mfma16(bf16x8 a, bf16x8 b, f32x4 c) {
  return __builtin_amdgcn_mfma_f32_16x16x32_bf16(a, b, c, 0, 0, 0);
}
static __device__ __forceinline__ void gload_lds16(const u16* g, u16* lds_base) {
  __builtin_amdgcn_global_load_lds(
      (const __attribute__((address_space(1))) u32*)g,
      (__attribute__((address_space(3))) u32*)lds_base, 16, 0, 0);
}

#define L2E 1.44269504088896340736f

// ---------------- split: f32 -> (hi, lo) bf16 ----------------
struct SplitArg { const float* s; u16* h; u16* l; int n4; };

__global__ void split6_kernel(SplitArg a0, SplitArg a1, SplitArg a2,
                              SplitArg a3, SplitArg a4, SplitArg a5) {
  SplitArg A = (blockIdx.z == 0) ? a0 : (blockIdx.z == 1) ? a1 : (blockIdx.z == 2) ? a2
             : (blockIdx.z == 3) ? a3 : (blockIdx.z == 4) ? a4 : a5;
  int i = blockIdx.x * blockDim.x + threadIdx.x;
  int stride = gridDim.x * blockDim.x;
  if (A.l) {
    for (; i < A.n4; i += stride) {
      float4 v = ((const float4*)A.s)[i];
      u16x4 h, l;
      h.x = f2bf(v.x); l.x = f2bf(v.x - bf2f(h.x));
      h.y = f2bf(v.y); l.y = f2bf(v.y - bf2f(h.y));
      h.z = f2bf(v.z); l.z = f2bf(v.z - bf2f(h.z));
      h.w = f2bf(v.w); l.w = f2bf(v.w - bf2f(h.w));
      ((u16x4*)A.h)[i] = h;
      ((u16x4*)A.l)[i] = l;
    }
  } else {  // hi-only (value: lo is never consumed)
    for (; i < A.n4; i += stride) {
      float4 v = ((const float4*)A.s)[i];
      u16x4 h;
      h.x = f2bf(v.x); h.y = f2bf(v.y); h.z = f2bf(v.z); h.w = f2bf(v.w);
      ((u16x4*)A.h)[i] = h;
    }
  }
}

// ---------------- amask -> bitmask (128 u32) ----------------
__global__ void pack_mask(const int* __restrict__ am, u32* __restrict__ pm) {
  int w = threadIdx.x;            // 0..127: [b][word]
  if (w < 128) {
    int base = (w >> 6) * 2048 + (w & 63) * 32;
    u32 bits = 0;
#pragma unroll
    for (int j = 0; j < 8; ++j) {
      int4 v = *(const int4*)(am + base + j * 4);
      bits |= (v.x ? 1u : 0u) << (4 * j) | (v.y ? 1u : 0u) << (4 * j + 1) |
              (v.z ? 1u : 0u) << (4 * j + 2) | (v.w ? 1u : 0u) << (4 * j + 3);
    }
    pm[w] = bits;
  }
}

// ---------------- projection GEMM (m97 structure, UNCHANGED from R6) ----------------
struct ProjArgs {
  const u16* xhi; const u16* xlo; const u16* whi; const u16* wlo;
  const float* bias; u16* ohi; u16* olo; int mode;
};

__global__ __launch_bounds__(256, 3) void proj_gemm(ProjArgs a0, ProjArgs a1, ProjArgs a2) {
  ProjArgs A = (blockIdx.z == 0) ? a0 : (blockIdx.z == 1) ? a1 : a2;
  __shared__ u16 As[128 * 64];
  __shared__ u16 Bs[128 * 64];
  const int t = threadIdx.x;
  const int l = t & 63, wid = t >> 6;
  const int g = l >> 4, ln = l & 15;
  const int wm = wid >> 1, wn = wid & 1;
  int bid = blockIdx.y * 8 + blockIdx.x;
  int sid = (bid & 7) * 32 + (bid >> 3);     // XCD swizzle (256 % 8 == 0)
  const int m0 = (sid >> 3) * 128, e0 = (sid & 7) * 128;

  f32x4 acc[4][4] = {};
  const int nkt = (A.mode == 2) ? 32 : 48;

  for (int kt = 0; kt < nkt; ++kt) {
    int kp = kt * 64;
    const u16* asrc = (kp < 2048) ? A.xhi : A.xlo;
    const u16* bsrc = (kp < 1024 || kp >= 2048) ? A.whi : A.wlo;
    int kc = kp & 1023;
#pragma unroll
    for (int r = 0; r < 4; ++r) {
      int cr = wid * 4 + r;
      int row = cr * 8 + (l >> 3);
      int col = (l & 7) * 8;
      gload_lds16(asrc + (size_t)(m0 + row) * 1024 + kc + col, As + cr * 512);
      gload_lds16(bsrc + (size_t)(e0 + row) * 1024 + kc + col, Bs + cr * 512);
    }
    __syncthreads();
#pragma unroll
    for (int ks = 0; ks < 2; ++ks) {
      bf16x8 af[4], bfv[4];
#pragma unroll
      for (int i = 0; i < 4; ++i) {
        af[i] = frag(As, (u32)(wm * 64 + i * 16 + ln) * 128 + ks * 64 + g * 16);
        bfv[i] = frag(Bs, (u32)(wn * 64 + i * 16 + ln) * 128 + ks * 64 + g * 16);
      }
#pragma unroll
      for (int i = 0; i < 4; ++i)
#pragma unroll
        for (int j = 0; j < 4; ++j)
          acc[i][j] = mfma16(af[i], bfv[j], acc[i][j]);
    }
    __syncthreads();
  }

#pragma unroll
  for (int i = 0; i < 4; ++i) {
#pragma unroll
    for (int j = 0; j < 4; ++j) {
      int e = e0 + wn * 64 + j * 16 + ln;
      int h = e >> 6, d = e & 63;
      float bias = A.bias[e];
      if (A.mode < 2) {
#pragma unroll
        for (int r = 0; r < 4; ++r) {
          int m = m0 + wm * 64 + i * 16 + g * 4 + r;
          float v = acc[i][j][r] + bias;
          if (A.mode == 0) v *= L2E;       // fold log2(e): attn uses exp2
          int b = m >> 11, s = m & 2047;
          size_t idx = ((size_t)((b * 16 + h) * 2048 + s)) * 64 + d;
          u16 hv = f2bf(v);
          A.ohi[idx] = hv;
          A.olo[idx] = f2bf(v - bf2f(hv));
        }
      } else {
        int m = m0 + wm * 64 + i * 16 + g * 4;
        int b = m >> 11, s = m & 2047;
        u16x4 pv;
#pragma unroll
        for (int r = 0; r < 4; ++r) pv[r] = f2bf(acc[i][j][r] + bias);
        size_t idx = ((size_t)((b * 16 + h) * 64 + d)) * 2048 + s;
        *(u16x4*)(A.ohi + idx) = pv;
      }
    }
  }
}

// ---------------- attention: 32-q waves, DMA-staged dbuf, 1 barrier/tile ----------------
// Each wave owns 32 q (two B-operand sets) x the full 64-k tile. The 16 K-frag
// LDS reads per tile now feed 48 MFMA (was 24), halving per-CU LDS-pipe time
// (the measured binder). All 4 waves read identical K/V fragments; q-slab
// widening amortizes that redundancy.
__global__ __launch_bounds__(256, 2) void attn_kernel(
    const u16* __restrict__ qhi, const u16* __restrict__ qlo,
    const u16* __restrict__ khi, const u16* __restrict__ klo,
    const u16* __restrict__ vt, const u32* __restrict__ pm,
    const float* __restrict__ dmask, float* __restrict__ out) {
  __shared__ u16 Ksh[2][64 * 64];
  __shared__ u16 Ksl[2][64 * 64];
  __shared__ u16 Vs[2][64 * 64];    // [d][k]
  __shared__ u16 Ps[4 * 32 * 64];   // per-wave [32 q][64 k]

  const int t = threadIdx.x, l = t & 63, wid = t >> 6;
  const int g = l >> 4, ln = l & 15;

  // 512 blocks; XCD swizzle (512 % 8 == 0 -> bijective): 64 blocks/XCD = 4 bh.
  int bid = blockIdx.x;
  int sid = (bid & 7) * 64 + (bid >> 3);
  const int qt = sid & 15, bh = sid >> 4, b = bh >> 4;
  const int q0 = qt * 128;
  const u32* pmb = pm + b * 64;

  size_t qg[2]; size_t dmrow[2];
#pragma unroll
  for (int qs = 0; qs < 2; ++qs) {
    int qrow = q0 + wid * 32 + qs * 16 + ln;
    qg[qs] = ((size_t)bh * 2048 + qrow) * 64;
    dmrow[qs] = ((size_t)bh * 2048 + qrow) * 2048;
  }

  bf16x8 qh[2][2], ql[2][2];
#pragma unroll
  for (int qs = 0; qs < 2; ++qs)
#pragma unroll
    for (int ks = 0; ks < 2; ++ks) {
      qh[qs][ks] = *(const bf16x8*)(qhi + qg[qs] + ks * 32 + g * 8);
      ql[qs][ks] = *(const bf16x8*)(qlo + qg[qs] + ks * 32 + g * 8);
    }

  // DMA-stage tile kt into buffer buf (linear LDS dest, inverse-swizzled src).
  auto stage = [&](int buf, int kt) {
    const int k0 = kt * 64;
    const size_t kbase = ((size_t)bh * 2048 + k0) * 64;
    u16* khd = Ksh[buf];
    u16* kld = Ksl[buf];
    u16* vd = Vs[buf];
#pragma unroll
    for (int r = 0; r < 2; ++r) {
      int cbase = wid * 64 + 256 * r;        // wave-uniform chunk base
      int c = cbase + l;                     // this lane's dest chunk
      int c2 = c ^ ((c >> 3) & 7);           // source chunk (involution)
      gload_lds16(khi + kbase + c2 * 8, khd + cbase * 8);
      gload_lds16(klo + kbase + c2 * 8, kld + cbase * 8);
      gload_lds16(vt + ((size_t)bh * 64 + (c2 >> 3)) * 2048 + k0 + (c2 & 7) * 8,
                  vd + cbase * 8);
    }
  };

  stage(0, 0);
  __syncthreads();

  f32x4 O[2][4] = {};
  float Zacc[2] = {0.f, 0.f};
  const u32 psb = (u32)(wid * 4096);

  for (int kt = 0; kt < 32; ++kt) {
    const int buf = kt & 1;
    const int k0 = kt * 64;
    // issue next tile's DMA; in flight across this whole compute phase
    if (kt < 31) stage(buf ^ 1, kt + 1);
    // dmask loads for THIS tile: issued now, consumed after QK^T (~1000 cy)
    float4 dm[2][4];
#pragma unroll
    for (int qs = 0; qs < 2; ++qs)
#pragma unroll
      for (int i = 0; i < 4; ++i)
        dm[qs][i] = *(const float4*)(dmask + dmrow[qs] + k0 + i * 16 + 4 * g);
    u32 m0 = pmb[2 * kt], m1 = pmb[2 * kt + 1];   // uniform -> s_load

    // QK^T (3-term split): A = K rows (LDS, shared across qsets), B = Q.
    f32x4 sc[2][4] = {};
#pragma unroll
    for (int ks = 0; ks < 2; ++ks) {
#pragma unroll
      for (int i = 0; i < 4; ++i) {
        u32 byt = sw((u32)((i * 16 + ln) * 128 + ks * 64 + g * 16));
        bf16x8 akh = frag(Ksh[buf], byt);
        bf16x8 akl = frag(Ksl[buf], byt);
#pragma unroll
        for (int qs = 0; qs < 2; ++qs) {
          sc[qs][i] = mfma16(akh, qh[qs][ks], sc[qs][i]);
          sc[qs][i] = mfma16(akh, ql[qs][ks], sc[qs][i]);
          sc[qs][i] = mfma16(akl, qh[qs][ks], sc[qs][i]);
        }
      }
    }

    // pad bits -> exp2 -> Z -> dropout -> packed P^T write (own slab, no sync)
#pragma unroll
    for (int qs = 0; qs < 2; ++qs)
#pragma unroll
      for (int i = 0; i < 4; ++i) {
        u32 mm = (i < 2 ? m0 : m1) >> (((i & 1) << 4) + 4 * g);
        float e0 = (mm & 1u) ? exp2f(sc[qs][i][0]) : 0.f;
        float e1 = (mm & 2u) ? exp2f(sc[qs][i][1]) : 0.f;
        float e2 = (mm & 4u) ? exp2f(sc[qs][i][2]) : 0.f;
        float e3 = (mm & 8u) ? exp2f(sc[qs][i][3]) : 0.f;
        Zacc[qs] += (e0 + e1) + (e2 + e3);
        u16x4 p;
        p.x = f2bf(e0 * dm[qs][i].x);
        p.y = f2bf(e1 * dm[qs][i].y);
        p.z = f2bf(e2 * dm[qs][i].z);
        p.w = f2bf(e3 * dm[qs][i].w);
        *(u16x4*)((char*)Ps + sw(psb + (qs * 16 + ln) * 128 + i * 32 + g * 8)) = p;
      }

    // PV: O^T = V^T . P^T; aV shared across qsets.
#pragma unroll
    for (int ks = 0; ks < 2; ++ks) {
      bf16x8 bP0 = frag(Ps, sw(psb + ln * 128 + ks * 64 + g * 16));
      bf16x8 bP1 = frag(Ps, sw(psb + (16 + ln) * 128 + ks * 64 + g * 16));
#pragma unroll
      for (int id = 0; id < 4; ++id) {
        bf16x8 aV = frag(Vs[buf], sw((u32)((id * 16 + ln) * 128 + ks * 64 + g * 16)));
        O[0][id] = mfma16(aV, bP0, O[0][id]);
        O[1][id] = mfma16(aV, bP1, O[1][id]);
      }
    }

    // single barrier: drains this buf's reads AND the block's DMA for buf^1
    __syncthreads();
  }

#pragma unroll
  for (int qs = 0; qs < 2; ++qs) {
    float z = Zacc[qs];
    z += __shfl_xor(z, 16, 64);
    z += __shfl_xor(z, 32, 64);
    float rz = 1.f / z;
#pragma unroll
    for (int id = 0; id < 4; ++id) {
      float4 o;
      o.x = O[qs][id][0] * rz; o.y = O[qs][id][1] * rz;
      o.z = O[qs][id][2] * rz; o.w = O[qs][id][3] * rz;
      *(float4*)(out + qg[qs] + id * 16 + 4 * g) = o;
    }
  }
}

// ---------------- host ----------------
extern "C" void kernel_launch(void* const* d_in, const int* in_sizes, int n_in,
                              void* d_out, int out_size, void* d_ws, size_t ws_size,
                              hipStream_t stream) {
  const float* query = (const float*)d_in[0];
  const float* keyt  = (const float*)d_in[1];
  const float* value = (const float*)d_in[2];
  const int*   amask = (const int*)d_in[3];
  const float* dmask = (const float*)d_in[4];
  const float* Wq = (const float*)d_in[5];
  const float* bq = (const float*)d_in[6];
  const float* Wk = (const float*)d_in[7];
  const float* bk = (const float*)d_in[8];
  const float* Wv = (const float*)d_in[9];
  const float* bv = (const float*)d_in[10];

  char* ws = (char*)d_ws;
  size_t off = 0;
  auto alloc = [&](size_t bytes) {
    char* p = ws + off;
    off += (bytes + 255) & ~(size_t)255;
    return p;
  };
  const size_t XB = (size_t)MM * E_ * sizeof(u16);   // 8 MB
  const size_t WB = (size_t)E_ * E_ * sizeof(u16);   // 2 MB

  u16 *xh[3], *xl[3], *wh[3], *wl[3];
  for (int i = 0; i < 3; ++i) { xh[i] = (u16*)alloc(XB); xl[i] = (u16*)alloc(XB); }
  for (int i = 0; i < 3; ++i) { wh[i] = (u16*)alloc(WB); wl[i] = (u16*)alloc(WB); }
  u16* q_hi = (u16*)alloc(XB);
  u16* q_lo = (u16*)alloc(XB);
  u16* k_hi = (u16*)alloc(XB);
  u16* k_lo = (u16*)alloc(XB);
  u16* v_t  = (u16*)alloc(XB);
  u32* pmask = (u32*)alloc(512);
  if (off > ws_size) return;

  SplitArg sa[6] = {
      {query, xh[0], xl[0], MM * E_ / 4}, {keyt, xh[1], xl[1], MM * E_ / 4},
      {value, xh[2], nullptr, MM * E_ / 4}, {Wq, wh[0], wl[0], E_ * E_ / 4},
      {Wk, wh[1], wl[1], E_ * E_ / 4},    {Wv, wh[2], wl[2], E_ * E_ / 4},
  };
  split6_kernel<<<dim3(512, 1, 6), 256, 0, stream>>>(sa[0], sa[1], sa[2], sa[3], sa[4], sa[5]);
  pack_mask<<<1, 128, 0, stream>>>(amask, pmask);

  ProjArgs pa[3] = {
      {xh[0], xl[0], wh[0], wl[0], bq, q_hi, q_lo, 0},
      {xh[1], xl[1], wh[1], wl[1], bk, k_hi, k_lo, 1},
      {xh[2], nullptr, wh[2], wl[2], bv, v_t, nullptr, 2},
  };
  proj_gemm<<<dim3(8, 32, 3), 256, 0, stream>>>(pa[0], pa[1], pa[2]);

  attn_kernel<<<dim3(512), 256, 0, stream>>>(
      q_hi, q_lo, k_hi, k_lo, v_t, pmask, dmask, (float*)d_out);
}

// Round 8
// 294.137 us; speedup vs baseline: 1.1134x; 1.1134x over previous
//
#include <hip/hip_runtime.h>

#define B_ 2
#define S_ 2048
#define E_ 1024
#define H_ 16
#define DH 64
#define MM (B_*S_)   // 4096
#define BHN (B_*H_)  // 32

typedef unsigned short u16;
typedef unsigned int u32;
typedef __attribute__((ext_vector_type(8))) __bf16 bf16x8;
typedef __attribute__((ext_vector_type(8))) _Float16 f16x8;
typedef __attribute__((ext_vector_type(4))) float f32x4;
typedef __attribute__((ext_vector_type(8))) u16 u16x8;
typedef __attribute__((ext_vector_type(4))) u16 u16x4;

static __device__ __forceinline__ u16 f2bf(float f) {   // split kernel only
  u32 u = __builtin_bit_cast(u32, f);
  u += 0x7fffu + ((u >> 16) & 1u);
  return (u16)(u >> 16);
}
static __device__ __forceinline__ float bf2f(u16 h) {
  return __builtin_bit_cast(float, (u32)h << 16);
}
// XOR swizzle for 128B-stride row-major LDS tiles.
static __device__ __forceinline__ u32 sw(u32 byte) {
  return byte ^ (((byte >> 7) & 7u) << 4);
}
static __device__ __forceinline__ bf16x8 frag(const u16* lds, u32 byte) {
  return *(const bf16x8*)((const char*)lds + byte);
}
static __device__ __forceinline__ f16x8 frag16(const u16* lds, u32 byte) {
  return *(const f16x8*)((const char*)lds + byte);
}
static __device__ __forceinline__ f32x4 mfma_bf(bf16x8 a, bf16x8 b, f32x4 c) {
  return __builtin_amdgcn_mfma_f32_16x16x32_bf16(a, b, c, 0, 0, 0);
}
static __device__ __forceinline__ f32x4 mfma_f16(f16x8 a, f16x8 b, f32x4 c) {
  return __builtin_amdgcn_mfma_f32_16x16x32_f16(a, b, c, 0, 0, 0);
}
static __device__ __forceinline__ void gload_lds16(const u16* g, u16* lds_base) {
  __builtin_amdgcn_global_load_lds(
      (const __attribute__((address_space(1))) u32*)g,
      (__attribute__((address_space(3))) u32*)lds_base, 16, 0, 0);
}

#define L2E 1.44269504088896340736f

// ---------------- split: f32 -> (hi, lo) bf16 ----------------
struct SplitArg { const float* s; u16* h; u16* l; int n4; };

__global__ void split6_kernel(SplitArg a0, SplitArg a1, SplitArg a2,
                              SplitArg a3, SplitArg a4, SplitArg a5) {
  SplitArg A = (blockIdx.z == 0) ? a0 : (blockIdx.z == 1) ? a1 : (blockIdx.z == 2) ? a2
             : (blockIdx.z == 3) ? a3 : (blockIdx.z == 4) ? a4 : a5;
  int i = blockIdx.x * blockDim.x + threadIdx.x;
  int stride = gridDim.x * blockDim.x;
  if (A.l) {
    for (; i < A.n4; i += stride) {
      float4 v = ((const float4*)A.s)[i];
      u16x4 h, l;
      h.x = f2bf(v.x); l.x = f2bf(v.x - bf2f(h.x));
      h.y = f2bf(v.y); l.y = f2bf(v.y - bf2f(h.y));
      h.z = f2bf(v.z); l.z = f2bf(v.z - bf2f(h.z));
      h.w = f2bf(v.w); l.w = f2bf(v.w - bf2f(h.w));
      ((u16x4*)A.h)[i] = h;
      ((u16x4*)A.l)[i] = l;
    }
  } else {  // hi-only (value: lo is never consumed)
    for (; i < A.n4; i += stride) {
      float4 v = ((const float4*)A.s)[i];
      u16x4 h;
      h.x = f2bf(v.x); h.y = f2bf(v.y); h.z = f2bf(v.z); h.w = f2bf(v.w);
      ((u16x4*)A.h)[i] = h;
    }
  }
}

// ---------------- amask -> bitmask (128 u32) ----------------
__global__ void pack_mask(const int* __restrict__ am, u32* __restrict__ pm) {
  int w = threadIdx.x;            // 0..127: [b][word]
  if (w < 128) {
    int base = (w >> 6) * 2048 + (w & 63) * 32;
    u32 bits = 0;
#pragma unroll
    for (int j = 0; j < 8; ++j) {
      int4 v = *(const int4*)(am + base + j * 4);
      bits |= (v.x ? 1u : 0u) << (4 * j) | (v.y ? 1u : 0u) << (4 * j + 1) |
              (v.z ? 1u : 0u) << (4 * j + 2) | (v.w ? 1u : 0u) << (4 * j + 3);
    }
    pm[w] = bits;
  }
}

// ---------------- projection GEMM (m97 structure) ----------------
// Compute: 3-term (Q,K) / 2-term (V) bf16-split GEMM, f32 accumulate.
// Output: mode 0 = Q fp16 (x L2E), mode 1 = K fp16, both (B,H,S,Dh);
//         mode 2 = V^T bf16 (B,H,Dh,S).
struct ProjArgs {
  const u16* xhi; const u16* xlo; const u16* whi; const u16* wlo;
  const float* bias; u16* ohi; int mode;
};

__global__ __launch_bounds__(256, 3) void proj_gemm(ProjArgs a0, ProjArgs a1, ProjArgs a2) {
  ProjArgs A = (blockIdx.z == 0) ? a0 : (blockIdx.z == 1) ? a1 : a2;
  __shared__ u16 As[128 * 64];
  __shared__ u16 Bs[128 * 64];
  const int t = threadIdx.x;
  const int l = t & 63, wid = t >> 6;
  const int g = l >> 4, ln = l & 15;
  const int wm = wid >> 1, wn = wid & 1;
  int bid = blockIdx.y * 8 + blockIdx.x;
  int sid = (bid & 7) * 32 + (bid >> 3);     // XCD swizzle (256 % 8 == 0)
  const int m0 = (sid >> 3) * 128, e0 = (sid & 7) * 128;

  f32x4 acc[4][4] = {};
  const int nkt = (A.mode == 2) ? 32 : 48;

  for (int kt = 0; kt < nkt; ++kt) {
    int kp = kt * 64;
    const u16* asrc = (kp < 2048) ? A.xhi : A.xlo;
    const u16* bsrc = (kp < 1024 || kp >= 2048) ? A.whi : A.wlo;
    int kc = kp & 1023;
#pragma unroll
    for (int r = 0; r < 4; ++r) {
      int cr = wid * 4 + r;
      int row = cr * 8 + (l >> 3);
      int col = (l & 7) * 8;
      gload_lds16(asrc + (size_t)(m0 + row) * 1024 + kc + col, As + cr * 512);
      gload_lds16(bsrc + (size_t)(e0 + row) * 1024 + kc + col, Bs + cr * 512);
    }
    __syncthreads();
#pragma unroll
    for (int ks = 0; ks < 2; ++ks) {
      bf16x8 af[4], bfv[4];
#pragma unroll
      for (int i = 0; i < 4; ++i) {
        af[i] = frag(As, (u32)(wm * 64 + i * 16 + ln) * 128 + ks * 64 + g * 16);
        bfv[i] = frag(Bs, (u32)(wn * 64 + i * 16 + ln) * 128 + ks * 64 + g * 16);
      }
#pragma unroll
      for (int i = 0; i < 4; ++i)
#pragma unroll
        for (int j = 0; j < 4; ++j)
          acc[i][j] = mfma_bf(af[i], bfv[j], acc[i][j]);
    }
    __syncthreads();
  }

#pragma unroll
  for (int i = 0; i < 4; ++i) {
#pragma unroll
    for (int j = 0; j < 4; ++j) {
      int e = e0 + wn * 64 + j * 16 + ln;
      int h = e >> 6, d = e & 63;
      float bias = A.bias[e];
      if (A.mode < 2) {
#pragma unroll
        for (int r = 0; r < 4; ++r) {
          int m = m0 + wm * 64 + i * 16 + g * 4 + r;
          float v = acc[i][j][r] + bias;
          if (A.mode == 0) v *= L2E;       // fold log2(e): attn uses exp2
          int b = m >> 11, s = m & 2047;
          size_t idx = ((size_t)((b * 16 + h) * 2048 + s)) * 64 + d;
          A.ohi[idx] = __builtin_bit_cast(u16, (_Float16)v);
        }
      } else {
        int m = m0 + wm * 64 + i * 16 + g * 4;
        int b = m >> 11, s = m & 2047;
        u16x4 pv;
#pragma unroll
        for (int r = 0; r < 4; ++r)
          pv[r] = __builtin_bit_cast(u16, (__bf16)(acc[i][j][r] + bias));
        size_t idx = ((size_t)((b * 16 + h) * 64 + d)) * 2048 + s;
        *(u16x4*)(A.ohi + idx) = pv;
      }
    }
  }
}

// ---------------- attention: fp16 QK^T, DMA-staged dbuf, 1 barrier/tile ----------------
// R6 geometry (1024 blocks, 4 waves x 16q, k-tile 64) with: single-term fp16
// QK^T (8 MFMA + 8 K-frag reads per wave-tile, was 24+16), native bf16 casts
// for P, 40 KB LDS -> 3 blocks/CU.
__global__ __launch_bounds__(256, 3) void attn_kernel(
    const u16* __restrict__ qf, const u16* __restrict__ kf,
    const u16* __restrict__ vt, const u32* __restrict__ pm,
    const float* __restrict__ dmask, float* __restrict__ out) {
  __shared__ u16 Ks[2][64 * 64];    // fp16 [k][d]
  __shared__ u16 Vs[2][64 * 64];    // bf16 [d][k]
  __shared__ u16 Ps[4 * 16 * 64];   // per-wave [16 q][64 k] bf16

  const int t = threadIdx.x, l = t & 63, wid = t >> 6;
  const int g = l >> 4, ln = l & 15;

  int bid = blockIdx.y * 32 + blockIdx.x;
  int sid = (bid & 7) * 128 + (bid >> 3);   // XCD swizzle: 4 bh per XCD
  const int qt = sid & 31, bh = sid >> 5, b = bh >> 4;
  const int q0 = qt * 64;
  const int qrow = q0 + wid * 16 + ln;
  const size_t qg = ((size_t)bh * 2048 + qrow) * 64;
  const u32* pmb = pm + b * 64;

  // Q fragments (fp16, L2E-folded at projection)
  f16x8 qv[2];
#pragma unroll
  for (int ks = 0; ks < 2; ++ks)
    qv[ks] = *(const f16x8*)(qf + qg + ks * 32 + g * 8);

  // hoisted per-thread source pointers (advance per tile)
  const float* dmp = dmask + ((size_t)bh * 2048 + qrow) * 2048 + 4 * g;
  const int c0 = wid * 64 + l, c1 = wid * 64 + 256 + l;      // dest chunks
  const int s0 = c0 ^ ((c0 >> 3) & 7), s1 = c1 ^ ((c1 >> 3) & 7);  // src chunks
  const u16* kp0 = kf + (size_t)bh * 2048 * 64 + s0 * 8;     // += 4096/tile
  const u16* kp1 = kf + (size_t)bh * 2048 * 64 + s1 * 8;
  const u16* vp0 = vt + ((size_t)bh * 64 + (s0 >> 3)) * 2048 + (s0 & 7) * 8;  // += 64/tile
  const u16* vp1 = vt + ((size_t)bh * 64 + (s1 >> 3)) * 2048 + (s1 & 7) * 8;

  auto stage = [&](int buf, int kt) {
    gload_lds16(kp0 + (size_t)kt * 4096, Ks[buf] + c0 * 8 - l * 8 + l * 8);  // keep simple below
  };
  (void)stage;

  // explicit staging (4 DMA/thread)
  auto stage_tile = [&](int buf, int kt) {
    u16* kd = Ks[buf];
    u16* vd = Vs[buf];
    gload_lds16(kp0 + (size_t)kt * 4096, kd + (wid * 64) * 8);
    gload_lds16(kp1 + (size_t)kt * 4096, kd + (wid * 64 + 256) * 8);
    gload_lds16(vp0 + kt * 64, vd + (wid * 64) * 8);
    gload_lds16(vp1 + kt * 64, vd + (wid * 64 + 256) * 8);
  };

  // dmask regs (prefetch one tile ahead)
  float4 dmc[4], dmn[4];
#pragma unroll
  for (int i = 0; i < 4; ++i) dmc[i] = *(const float4*)(dmp + i * 16);

  stage_tile(0, 0);
  __syncthreads();

  f32x4 O[4] = {};
  float Zacc = 0.f;
  const u32 psbase = (u32)(wid * 2048 + ln * 128);
  // hoisted P LDS byte offsets
  u32 pw[4], pr[2];
#pragma unroll
  for (int i = 0; i < 4; ++i) pw[i] = sw(psbase + i * 32 + g * 8);
#pragma unroll
  for (int ks = 0; ks < 2; ++ks) pr[ks] = sw(psbase + ks * 64 + g * 16);

  for (int kt = 0; kt < 32; ++kt) {
    const int buf = kt & 1;
    if (kt < 31) {
      stage_tile(buf ^ 1, kt + 1);
      const float* dmn_p = dmp + (kt + 1) * 64;
#pragma unroll
      for (int i = 0; i < 4; ++i) dmn[i] = *(const float4*)(dmn_p + i * 16);
    }
    u32 m0 = pmb[2 * kt], m1 = pmb[2 * kt + 1];   // block-uniform -> s_load

    // QK^T: single-term fp16. A = K rows (LDS), B = Q (regs).
    f32x4 sc[4] = {};
#pragma unroll
    for (int ks = 0; ks < 2; ++ks) {
#pragma unroll
      for (int i = 0; i < 4; ++i) {
        f16x8 ak = frag16(Ks[buf], sw((u32)((i * 16 + ln) * 128 + ks * 64 + g * 16)));
        sc[i] = mfma_f16(ak, qv[ks], sc[i]);
      }
    }

    // pad bits -> exp2 -> Z -> dropout -> P (bf16, native cvt) to own slab
#pragma unroll
    for (int i = 0; i < 4; ++i) {
      u32 mm = (i < 2 ? m0 : m1) >> (((i & 1) << 4) + 4 * g);
      float e0 = (mm & 1u) ? exp2f(sc[i][0]) : 0.f;
      float e1 = (mm & 2u) ? exp2f(sc[i][1]) : 0.f;
      float e2 = (mm & 4u) ? exp2f(sc[i][2]) : 0.f;
      float e3 = (mm & 8u) ? exp2f(sc[i][3]) : 0.f;
      Zacc += (e0 + e1) + (e2 + e3);
      u16x4 p;
      p.x = __builtin_bit_cast(u16, (__bf16)(e0 * dmc[i].x));
      p.y = __builtin_bit_cast(u16, (__bf16)(e1 * dmc[i].y));
      p.z = __builtin_bit_cast(u16, (__bf16)(e2 * dmc[i].z));
      p.w = __builtin_bit_cast(u16, (__bf16)(e3 * dmc[i].w));
      *(u16x4*)((char*)Ps + pw[i]) = p;
    }

    // PV: O^T = V^T . P^T (bf16)
#pragma unroll
    for (int ks = 0; ks < 2; ++ks) {
      bf16x8 bP = frag(Ps, pr[ks]);
#pragma unroll
      for (int id = 0; id < 4; ++id) {
        bf16x8 aV = frag(Vs[buf], sw((u32)((id * 16 + ln) * 128 + ks * 64 + g * 16)));
        O[id] = mfma_bf(aV, bP, O[id]);
      }
    }

    __syncthreads();   // drains this buf's reads + DMA for buf^1
    if (kt < 31) {
#pragma unroll
      for (int i = 0; i < 4; ++i) dmc[i] = dmn[i];
    }
  }

  float z = Zacc;
  z += __shfl_xor(z, 16, 64);
  z += __shfl_xor(z, 32, 64);
  float rz = 1.f / z;

#pragma unroll
  for (int id = 0; id < 4; ++id) {
    float4 o;
    o.x = O[id][0] * rz; o.y = O[id][1] * rz;
    o.z = O[id][2] * rz; o.w = O[id][3] * rz;
    *(float4*)(out + qg + id * 16 + 4 * g) = o;
  }
}

// ---------------- host ----------------
extern "C" void kernel_launch(void* const* d_in, const int* in_sizes, int n_in,
                              void* d_out, int out_size, void* d_ws, size_t ws_size,
                              hipStream_t stream) {
  const float* query = (const float*)d_in[0];
  const float* keyt  = (const float*)d_in[1];
  const float* value = (const float*)d_in[2];
  const int*   amask = (const int*)d_in[3];
  const float* dmask = (const float*)d_in[4];
  const float* Wq = (const float*)d_in[5];
  const float* bq = (const float*)d_in[6];
  const float* Wk = (const float*)d_in[7];
  const float* bk = (const float*)d_in[8];
  const float* Wv = (const float*)d_in[9];
  const float* bv = (const float*)d_in[10];

  char* ws = (char*)d_ws;
  size_t off = 0;
  auto alloc = [&](size_t bytes) {
    char* p = ws + off;
    off += (bytes + 255) & ~(size_t)255;
    return p;
  };
  const size_t XB = (size_t)MM * E_ * sizeof(u16);   // 8 MB
  const size_t WB = (size_t)E_ * E_ * sizeof(u16);   // 2 MB

  u16 *xh[3], *xl[3], *wh[3], *wl[3];
  for (int i = 0; i < 3; ++i) { xh[i] = (u16*)alloc(XB); xl[i] = (u16*)alloc(XB); }
  for (int i = 0; i < 3; ++i) { wh[i] = (u16*)alloc(WB); wl[i] = (u16*)alloc(WB); }
  u16* q_f16 = (u16*)alloc(XB);
  u16* k_f16 = (u16*)alloc(XB);
  u16* v_t   = (u16*)alloc(XB);
  u32* pmask = (u32*)alloc(512);
  if (off > ws_size) return;

  SplitArg sa[6] = {
      {query, xh[0], xl[0], MM * E_ / 4}, {keyt, xh[1], xl[1], MM * E_ / 4},
      {value, xh[2], nullptr, MM * E_ / 4}, {Wq, wh[0], wl[0], E_ * E_ / 4},
      {Wk, wh[1], wl[1], E_ * E_ / 4},    {Wv, wh[2], wl[2], E_ * E_ / 4},
  };
  split6_kernel<<<dim3(512, 1, 6), 256, 0, stream>>>(sa[0], sa[1], sa[2], sa[3], sa[4], sa[5]);
  pack_mask<<<1, 128, 0, stream>>>(amask, pmask);

  ProjArgs pa[3] = {
      {xh[0], xl[0], wh[0], wl[0], bq, q_f16, 0},
      {xh[1], xl[1], wh[1], wl[1], bk, k_f16, 1},
      {xh[2], nullptr, wh[2], wl[2], bv, v_t, 2},
  };
  proj_gemm<<<dim3(8, 32, 3), 256, 0, stream>>>(pa[0], pa[1], pa[2]);

  attn_kernel<<<dim3(32, 32), 256, 0, stream>>>(
      q_f16, k_f16, v_t, pmask, dmask, (float*)d_out);
}

// Round 9
// 284.477 us; speedup vs baseline: 1.1512x; 1.0340x over previous
//
#include <hip/hip_runtime.h>

#define B_ 2
#define S_ 2048
#define E_ 1024
#define H_ 16
#define DH 64
#define MM (B_*S_)   // 4096
#define BHN (B_*H_)  // 32
#define KSPLIT 4

typedef unsigned short u16;
typedef unsigned int u32;
typedef __attribute__((ext_vector_type(8))) __bf16 bf16x8;
typedef __attribute__((ext_vector_type(8))) _Float16 f16x8;
typedef __attribute__((ext_vector_type(4))) float f32x4;
typedef __attribute__((ext_vector_type(8))) u16 u16x8;
typedef __attribute__((ext_vector_type(4))) u16 u16x4;

static __device__ __forceinline__ u16 f2bf(float f) {   // split kernel only
  u32 u = __builtin_bit_cast(u32, f);
  u += 0x7fffu + ((u >> 16) & 1u);
  return (u16)(u >> 16);
}
static __device__ __forceinline__ float bf2f(u16 h) {
  return __builtin_bit_cast(float, (u32)h << 16);
}
// XOR swizzle for 128B-stride row-major LDS tiles.
static __device__ __forceinline__ u32 sw(u32 byte) {
  return byte ^ (((byte >> 7) & 7u) << 4);
}
static __device__ __forceinline__ bf16x8 frag(const u16* lds, u32 byte) {
  return *(const bf16x8*)((const char*)lds + byte);
}
static __device__ __forceinline__ f16x8 frag16(const u16* lds, u32 byte) {
  return *(const f16x8*)((const char*)lds + byte);
}
static __device__ __forceinline__ f32x4 mfma_bf(bf16x8 a, bf16x8 b, f32x4 c) {
  return __builtin_amdgcn_mfma_f32_16x16x32_bf16(a, b, c, 0, 0, 0);
}
static __device__ __forceinline__ f32x4 mfma_f16(f16x8 a, f16x8 b, f32x4 c) {
  return __builtin_amdgcn_mfma_f32_16x16x32_f16(a, b, c, 0, 0, 0);
}
static __device__ __forceinline__ void gload_lds16(const u16* g, u16* lds_base) {
  __builtin_amdgcn_global_load_lds(
      (const __attribute__((address_space(1))) u32*)g,
      (__attribute__((address_space(3))) u32*)lds_base, 16, 0, 0);
}

#define L2E 1.44269504088896340736f

// ---------------- split: f32 -> (hi, lo) bf16 ----------------
struct SplitArg { const float* s; u16* h; u16* l; int n4; };

__global__ void split6_kernel(SplitArg a0, SplitArg a1, SplitArg a2,
                              SplitArg a3, SplitArg a4, SplitArg a5) {
  SplitArg A = (blockIdx.z == 0) ? a0 : (blockIdx.z == 1) ? a1 : (blockIdx.z == 2) ? a2
             : (blockIdx.z == 3) ? a3 : (blockIdx.z == 4) ? a4 : a5;
  int i = blockIdx.x * blockDim.x + threadIdx.x;
  int stride = gridDim.x * blockDim.x;
  if (A.l) {
    for (; i < A.n4; i += stride) {
      float4 v = ((const float4*)A.s)[i];
      u16x4 h, l;
      h.x = f2bf(v.x); l.x = f2bf(v.x - bf2f(h.x));
      h.y = f2bf(v.y); l.y = f2bf(v.y - bf2f(h.y));
      h.z = f2bf(v.z); l.z = f2bf(v.z - bf2f(h.z));
      h.w = f2bf(v.w); l.w = f2bf(v.w - bf2f(h.w));
      ((u16x4*)A.h)[i] = h;
      ((u16x4*)A.l)[i] = l;
    }
  } else {  // hi-only (value: lo is never consumed)
    for (; i < A.n4; i += stride) {
      float4 v = ((const float4*)A.s)[i];
      u16x4 h;
      h.x = f2bf(v.x); h.y = f2bf(v.y); h.z = f2bf(v.z); h.w = f2bf(v.w);
      ((u16x4*)A.h)[i] = h;
    }
  }
}

// ---------------- amask -> bitmask (128 u32) ----------------
__global__ void pack_mask(const int* __restrict__ am, u32* __restrict__ pm) {
  int w = threadIdx.x;            // 0..127: [b][word]
  if (w < 128) {
    int base = (w >> 6) * 2048 + (w & 63) * 32;
    u32 bits = 0;
#pragma unroll
    for (int j = 0; j < 8; ++j) {
      int4 v = *(const int4*)(am + base + j * 4);
      bits |= (v.x ? 1u : 0u) << (4 * j) | (v.y ? 1u : 0u) << (4 * j + 1) |
              (v.z ? 1u : 0u) << (4 * j + 2) | (v.w ? 1u : 0u) << (4 * j + 3);
    }
    pm[w] = bits;
  }
}

// ---------------- projection GEMM (m97 structure, UNCHANGED from R8) ----------------
struct ProjArgs {
  const u16* xhi; const u16* xlo; const u16* whi; const u16* wlo;
  const float* bias; u16* ohi; int mode;
};

__global__ __launch_bounds__(256, 3) void proj_gemm(ProjArgs a0, ProjArgs a1, ProjArgs a2) {
  ProjArgs A = (blockIdx.z == 0) ? a0 : (blockIdx.z == 1) ? a1 : a2;
  __shared__ u16 As[128 * 64];
  __shared__ u16 Bs[128 * 64];
  const int t = threadIdx.x;
  const int l = t & 63, wid = t >> 6;
  const int g = l >> 4, ln = l & 15;
  const int wm = wid >> 1, wn = wid & 1;
  int bid = blockIdx.y * 8 + blockIdx.x;
  int sid = (bid & 7) * 32 + (bid >> 3);     // XCD swizzle (256 % 8 == 0)
  const int m0 = (sid >> 3) * 128, e0 = (sid & 7) * 128;

  f32x4 acc[4][4] = {};
  const int nkt = (A.mode == 2) ? 32 : 48;

  for (int kt = 0; kt < nkt; ++kt) {
    int kp = kt * 64;
    const u16* asrc = (kp < 2048) ? A.xhi : A.xlo;
    const u16* bsrc = (kp < 1024 || kp >= 2048) ? A.whi : A.wlo;
    int kc = kp & 1023;
#pragma unroll
    for (int r = 0; r < 4; ++r) {
      int cr = wid * 4 + r;
      int row = cr * 8 + (l >> 3);
      int col = (l & 7) * 8;
      gload_lds16(asrc + (size_t)(m0 + row) * 1024 + kc + col, As + cr * 512);
      gload_lds16(bsrc + (size_t)(e0 + row) * 1024 + kc + col, Bs + cr * 512);
    }
    __syncthreads();
#pragma unroll
    for (int ks = 0; ks < 2; ++ks) {
      bf16x8 af[4], bfv[4];
#pragma unroll
      for (int i = 0; i < 4; ++i) {
        af[i] = frag(As, (u32)(wm * 64 + i * 16 + ln) * 128 + ks * 64 + g * 16);
        bfv[i] = frag(Bs, (u32)(wn * 64 + i * 16 + ln) * 128 + ks * 64 + g * 16);
      }
#pragma unroll
      for (int i = 0; i < 4; ++i)
#pragma unroll
        for (int j = 0; j < 4; ++j)
          acc[i][j] = mfma_bf(af[i], bfv[j], acc[i][j]);
    }
    __syncthreads();
  }

#pragma unroll
  for (int i = 0; i < 4; ++i) {
#pragma unroll
    for (int j = 0; j < 4; ++j) {
      int e = e0 + wn * 64 + j * 16 + ln;
      int h = e >> 6, d = e & 63;
      float bias = A.bias[e];
      if (A.mode < 2) {
#pragma unroll
        for (int r = 0; r < 4; ++r) {
          int m = m0 + wm * 64 + i * 16 + g * 4 + r;
          float v = acc[i][j][r] + bias;
          if (A.mode == 0) v *= L2E;       // fold log2(e): attn uses exp2
          int b = m >> 11, s = m & 2047;
          size_t idx = ((size_t)((b * 16 + h) * 2048 + s)) * 64 + d;
          A.ohi[idx] = __builtin_bit_cast(u16, (_Float16)v);
        }
      } else {
        int m = m0 + wm * 64 + i * 16 + g * 4;
        int b = m >> 11, s = m & 2047;
        u16x4 pv;
#pragma unroll
        for (int r = 0; r < 4; ++r)
          pv[r] = __builtin_bit_cast(u16, (__bf16)(acc[i][j][r] + bias));
        size_t idx = ((size_t)((b * 16 + h) * 64 + d)) * 2048 + s;
        *(u16x4*)(A.ohi + idx) = pv;
      }
    }
  }
}

// ---------------- attention: SPLIT-K (4 chunks of 512 keys) ----------------
// Each block: one 64-q slab x one 512-key chunk (8 k-tiles). Writes partial
// unnormalized O (f32) + partial Z. 4x block count breaks the lockstep
// latency chain (the measured binder); combine kernel reduces.
__global__ __launch_bounds__(256, 3) void attn_kernel(
    const u16* __restrict__ qf, const u16* __restrict__ kf,
    const u16* __restrict__ vt, const u32* __restrict__ pm,
    const float* __restrict__ dmask, float* __restrict__ opart,
    float* __restrict__ zpart) {
  __shared__ u16 Ks[2][64 * 64];    // fp16 [k][d]
  __shared__ u16 Vs[2][64 * 64];    // bf16 [d][k]
  __shared__ u16 Ps[4 * 16 * 64];   // per-wave [16 q][64 k] bf16

  const int t = threadIdx.x, l = t & 63, wid = t >> 6;
  const int g = l >> 4, ln = l & 15;

  int bid = blockIdx.y * 32 + blockIdx.x;
  int sid = (bid & 7) * 128 + (bid >> 3);   // XCD swizzle: 4 bh per XCD
  const int qt = sid & 31, bh = sid >> 5, b = bh >> 4;
  const int kc = blockIdx.z;                // k-chunk: same XCD as siblings
  const int q0 = qt * 64;
  const int qrow = q0 + wid * 16 + ln;
  const size_t qg = ((size_t)bh * 2048 + qrow) * 64;
  const u32* pmb = pm + b * 64;

  // Q fragments (fp16, L2E-folded at projection)
  f16x8 qv[2];
#pragma unroll
  for (int ks = 0; ks < 2; ++ks)
    qv[ks] = *(const f16x8*)(qf + qg + ks * 32 + g * 8);

  // hoisted per-thread source pointers (global k-tile index kt2 advances them)
  const float* dmp = dmask + ((size_t)bh * 2048 + qrow) * 2048 + 4 * g;
  const int c0 = wid * 64 + l, c1 = wid * 64 + 256 + l;            // dest chunks
  const int s0 = c0 ^ ((c0 >> 3) & 7), s1 = c1 ^ ((c1 >> 3) & 7);  // src chunks
  const u16* kp0 = kf + (size_t)bh * 2048 * 64 + s0 * 8;
  const u16* kp1 = kf + (size_t)bh * 2048 * 64 + s1 * 8;
  const u16* vp0 = vt + ((size_t)bh * 64 + (s0 >> 3)) * 2048 + (s0 & 7) * 8;
  const u16* vp1 = vt + ((size_t)bh * 64 + (s1 >> 3)) * 2048 + (s1 & 7) * 8;

  auto stage_tile = [&](int buf, int kt2) {
    u16* kd = Ks[buf];
    u16* vd = Vs[buf];
    gload_lds16(kp0 + (size_t)kt2 * 4096, kd + (wid * 64) * 8);
    gload_lds16(kp1 + (size_t)kt2 * 4096, kd + (wid * 64 + 256) * 8);
    gload_lds16(vp0 + kt2 * 64, vd + (wid * 64) * 8);
    gload_lds16(vp1 + kt2 * 64, vd + (wid * 64 + 256) * 8);
  };

  // dmask regs (prefetch one tile ahead)
  float4 dmc[4], dmn[4];
  const float* dm0 = dmp + kc * 8 * 64;
#pragma unroll
  for (int i = 0; i < 4; ++i) dmc[i] = *(const float4*)(dm0 + i * 16);

  stage_tile(0, kc * 8);
  __syncthreads();

  f32x4 O[4] = {};
  float Zacc = 0.f;
  const u32 psbase = (u32)(wid * 2048 + ln * 128);
  u32 pw[4], pr[2];
#pragma unroll
  for (int i = 0; i < 4; ++i) pw[i] = sw(psbase + i * 32 + g * 8);
#pragma unroll
  for (int ks = 0; ks < 2; ++ks) pr[ks] = sw(psbase + ks * 64 + g * 16);

  for (int kt = 0; kt < 8; ++kt) {
    const int buf = kt & 1;
    const int kt2 = kc * 8 + kt;
    if (kt < 7) {
      stage_tile(buf ^ 1, kt2 + 1);
      const float* dmn_p = dmp + (kt2 + 1) * 64;
#pragma unroll
      for (int i = 0; i < 4; ++i) dmn[i] = *(const float4*)(dmn_p + i * 16);
    }
    u32 m0 = pmb[2 * kt2], m1 = pmb[2 * kt2 + 1];   // block-uniform -> s_load

    // QK^T: single-term fp16. A = K rows (LDS), B = Q (regs).
    f32x4 sc[4] = {};
#pragma unroll
    for (int ks = 0; ks < 2; ++ks) {
#pragma unroll
      for (int i = 0; i < 4; ++i) {
        f16x8 ak = frag16(Ks[buf], sw((u32)((i * 16 + ln) * 128 + ks * 64 + g * 16)));
        sc[i] = mfma_f16(ak, qv[ks], sc[i]);
      }
    }

    // pad bits -> exp2 -> Z -> dropout -> P (bf16) to own slab
#pragma unroll
    for (int i = 0; i < 4; ++i) {
      u32 mm = (i < 2 ? m0 : m1) >> (((i & 1) << 4) + 4 * g);
      float e0 = (mm & 1u) ? exp2f(sc[i][0]) : 0.f;
      float e1 = (mm & 2u) ? exp2f(sc[i][1]) : 0.f;
      float e2 = (mm & 4u) ? exp2f(sc[i][2]) : 0.f;
      float e3 = (mm & 8u) ? exp2f(sc[i][3]) : 0.f;
      Zacc += (e0 + e1) + (e2 + e3);
      u16x4 p;
      p.x = __builtin_bit_cast(u16, (__bf16)(e0 * dmc[i].x));
      p.y = __builtin_bit_cast(u16, (__bf16)(e1 * dmc[i].y));
      p.z = __builtin_bit_cast(u16, (__bf16)(e2 * dmc[i].z));
      p.w = __builtin_bit_cast(u16, (__bf16)(e3 * dmc[i].w));
      *(u16x4*)((char*)Ps + pw[i]) = p;
    }

    // PV: O^T = V^T . P^T (bf16)
#pragma unroll
    for (int ks = 0; ks < 2; ++ks) {
      bf16x8 bP = frag(Ps, pr[ks]);
#pragma unroll
      for (int id = 0; id < 4; ++id) {
        bf16x8 aV = frag(Vs[buf], sw((u32)((id * 16 + ln) * 128 + ks * 64 + g * 16)));
        O[id] = mfma_bf(aV, bP, O[id]);
      }
    }

    __syncthreads();   // drains this buf's reads + DMA for buf^1
    if (kt < 7) {
#pragma unroll
      for (int i = 0; i < 4; ++i) dmc[i] = dmn[i];
    }
  }

  // partial Z (summed over the 4 g-lane groups of each qrow)
  float z = Zacc;
  z += __shfl_xor(z, 16, 64);
  z += __shfl_xor(z, 32, 64);
  const int row = bh * 2048 + qrow;
  if (g == 0) zpart[kc * (BHN * S_) + row] = z;

  // partial O (unnormalized)
  float* opb = opart + ((size_t)kc * (BHN * S_) + row) * 64;
#pragma unroll
  for (int id = 0; id < 4; ++id) {
    float4 o;
    o.x = O[id][0]; o.y = O[id][1]; o.z = O[id][2]; o.w = O[id][3];
    *(float4*)(opb + id * 16 + 4 * g) = o;
  }
}

// ---------------- combine: out = sum_kc Opart / sum_kc Zpart ----------------
__global__ void combine_kernel(const float* __restrict__ op,
                               const float* __restrict__ zp,
                               float* __restrict__ out) {
  int tid = blockIdx.x * blockDim.x + threadIdx.x;   // 1M threads, 1 float4 each
  int row = tid >> 4, d4 = tid & 15;
  float4 o = make_float4(0.f, 0.f, 0.f, 0.f);
  float z = 0.f;
#pragma unroll
  for (int kc = 0; kc < KSPLIT; ++kc) {
    float4 v = *(const float4*)(op + ((size_t)kc * (BHN * S_) + row) * 64 + d4 * 4);
    o.x += v.x; o.y += v.y; o.z += v.z; o.w += v.w;
    z += zp[kc * (BHN * S_) + row];
  }
  float rz = 1.f / z;
  float4 r;
  r.x = o.x * rz; r.y = o.y * rz; r.z = o.z * rz; r.w = o.w * rz;
  *(float4*)(out + (size_t)row * 64 + d4 * 4) = r;
}

// ---------------- host ----------------
extern "C" void kernel_launch(void* const* d_in, const int* in_sizes, int n_in,
                              void* d_out, int out_size, void* d_ws, size_t ws_size,
                              hipStream_t stream) {
  const float* query = (const float*)d_in[0];
  const float* keyt  = (const float*)d_in[1];
  const float* value = (const float*)d_in[2];
  const int*   amask = (const int*)d_in[3];
  const float* dmask = (const float*)d_in[4];
  const float* Wq = (const float*)d_in[5];
  const float* bq = (const float*)d_in[6];
  const float* Wk = (const float*)d_in[7];
  const float* bk = (const float*)d_in[8];
  const float* Wv = (const float*)d_in[9];
  const float* bv = (const float*)d_in[10];

  char* ws = (char*)d_ws;
  size_t off = 0;
  auto alloc = [&](size_t bytes) {
    char* p = ws + off;
    off += (bytes + 255) & ~(size_t)255;
    return p;
  };
  const size_t XB = (size_t)MM * E_ * sizeof(u16);   // 8 MB
  const size_t WB = (size_t)E_ * E_ * sizeof(u16);   // 2 MB

  u16 *xh[3], *xl[3], *wh[3], *wl[3];
  for (int i = 0; i < 3; ++i) { xh[i] = (u16*)alloc(XB); xl[i] = (u16*)alloc(XB); }
  for (int i = 0; i < 3; ++i) { wh[i] = (u16*)alloc(WB); wl[i] = (u16*)alloc(WB); }
  u16* q_f16 = (u16*)alloc(XB);
  u16* k_f16 = (u16*)alloc(XB);
  u16* v_t   = (u16*)alloc(XB);
  u32* pmask = (u32*)alloc(512);
  float* opart = (float*)alloc((size_t)KSPLIT * BHN * S_ * 64 * 4);  // 64 MB
  float* zpart = (float*)alloc((size_t)KSPLIT * BHN * S_ * 4);      // 1 MB
  if (off > ws_size) return;

  SplitArg sa[6] = {
      {query, xh[0], xl[0], MM * E_ / 4}, {keyt, xh[1], xl[1], MM * E_ / 4},
      {value, xh[2], nullptr, MM * E_ / 4}, {Wq, wh[0], wl[0], E_ * E_ / 4},
      {Wk, wh[1], wl[1], E_ * E_ / 4},    {Wv, wh[2], wl[2], E_ * E_ / 4},
  };
  split6_kernel<<<dim3(512, 1, 6), 256, 0, stream>>>(sa[0], sa[1], sa[2], sa[3], sa[4], sa[5]);
  pack_mask<<<1, 128, 0, stream>>>(amask, pmask);

  ProjArgs pa[3] = {
      {xh[0], xl[0], wh[0], wl[0], bq, q_f16, 0},
      {xh[1], xl[1], wh[1], wl[1], bk, k_f16, 1},
      {xh[2], nullptr, wh[2], wl[2], bv, v_t, 2},
  };
  proj_gemm<<<dim3(8, 32, 3), 256, 0, stream>>>(pa[0], pa[1], pa[2]);

  attn_kernel<<<dim3(32, 32, KSPLIT), 256, 0, stream>>>(
      q_f16, k_f16, v_t, pmask, dmask, opart, zpart);

  combine_kernel<<<(BHN * S_ * 64 / 4) / 256, 256, 0, stream>>>(
      opart, zpart, (float*)d_out);
}